// Round 6
// baseline (742.228 us; speedup 1.0000x reference)
//
#include <hip/hip_runtime.h>
#include <hip/hip_bf16.h>
#include <string.h>

// Sizes
#define V_    50000
#define VO_   50050
#define E_    128
#define H_    256
#define S_    400
#define B_    128
#define OOV_  50

typedef __bf16  bf16x8 __attribute__((ext_vector_type(8)));
typedef float   f32x4  __attribute__((ext_vector_type(4)));
typedef unsigned short u16;
typedef unsigned int   u32;

__device__ __forceinline__ float sigm(float x){ return 1.f/(1.f+__expf(-x)); }
__device__ __forceinline__ u16 f2bits(float f){ __hip_bfloat16 h = __float2bfloat16(f); u16 b; memcpy(&b, &h, 2); return b; }

// ---------------- K0: zero ctx accumulator ----------------
__global__ void k_init(float* p, int n){
    int i = blockIdx.x*256 + threadIdx.x;
    if (i < n) p[i] = 0.f;
}

// ---------------- K1: embed + x + LSTM cell + dec_feat (all fp32) ----------------
__global__ void k_small1(const int* tok, const float* emb, const float* ctxv,
                         const float* h0, const float* c0,
                         const float* Wi, const float* bi,
                         const float* W_ih, const float* W_hh,
                         const float* b_ih, const float* b_hh,
                         const float* aws,
                         float* o_ht, float* o_ct,
                         float* ws_status, float* ws_x, float* ws_dec)
{
    int b = blockIdx.x, t = threadIdx.x;
    __shared__ float in_vec[640];   // [context_vec(512), embed(128)]
    __shared__ float h0s[256];
    __shared__ float xs[128];
    __shared__ float gates[1024];
    __shared__ float st[512];
    for (int i = t; i < 512; i += 256) in_vec[i] = ctxv[b*512+i];
    int tk = tok[b];
    if (t < 128) in_vec[512+t] = emb[tk*128+t];
    h0s[t] = h0[b*256+t];
    __syncthreads();
    if (t < 128) {
        float s = bi[t];
        const float* wr = Wi + t*640;
        for (int k = 0; k < 640; k++) s += wr[k] * in_vec[k];
        xs[t] = s; ws_x[b*128+t] = s;
    }
    __syncthreads();
    for (int g = t; g < 1024; g += 256) {
        float s = b_ih[g] + b_hh[g];
        const float* wr = W_ih + g*128;
        for (int k = 0; k < 128; k++) s += wr[k] * xs[k];
        const float* hr = W_hh + g*256;
        for (int k = 0; k < 256; k++) s += hr[k] * h0s[k];
        gates[g] = s;
    }
    __syncthreads();
    {   // torch gate order i,f,g,o
        float ig = sigm(gates[t]);
        float fg = sigm(gates[256+t]);
        float gg = tanhf(gates[512+t]);
        float og = sigm(gates[768+t]);
        float c  = fg * c0[b*256+t] + ig * gg;
        float h  = og * tanhf(c);
        st[t] = h; st[256+t] = c;
        o_ht[b*256+t] = h; o_ct[b*256+t] = c;
        ws_status[b*512+t] = h; ws_status[b*512+256+t] = c;
    }
    __syncthreads();
    for (int d = t; d < 512; d += 256) {
        float s = 0.f;
        const float* wr = aws + d*512;
        for (int k = 0; k < 512; k++) s += wr[k] * st[k];
        ws_dec[b*512+d] = s;
    }
}

// ---------------- K3: enc_feat GEMM (fp32->bf16 staged MFMA) fused tanh+dot(att_v) ----------------
// Each block: 64 rows (M) x full N=512; 4 waves, each 64x128. e_t written directly.
__global__ __launch_bounds__(256) void k_attn(
    const float* enc, const float* wh, const float* dec, const float* cov,
    const float* wc, const float* bc, const float* vv, float* e_t)
{
    const int M0 = blockIdx.x * 64;
    int t = threadIdx.x;
    int wave = t >> 6, lane = t & 63, quad = lane >> 4, l16 = lane & 15;
    __shared__ __align__(16) u16 As[64*40];     // row stride 40 (pad)
    __shared__ __align__(16) u16 Bs[512*40];
    __shared__ float part[4][64];
    f32x4 acc[4][8] = {};
    for (int kt = 0; kt < 512; kt += 32) {
        #pragma unroll
        for (int j = 0; j < 2; j++) {           // A: 64 rows x 32 k (fp32 -> 4 bf16 per copy)
            int gi = j*256 + t;
            int row = gi >> 3, c4 = gi & 7;
            float4 v = *(const float4*)&enc[(size_t)(M0+row)*512 + kt + c4*4];
            ushort4 pk = { f2bits(v.x), f2bits(v.y), f2bits(v.z), f2bits(v.w) };
            *(ushort4*)&As[row*40 + c4*4] = pk;
        }
        #pragma unroll
        for (int j = 0; j < 16; j++) {          // B: 512 rows x 32 k
            int gi = j*256 + t;
            int row = gi >> 3, c4 = gi & 7;
            float4 v = *(const float4*)&wh[(size_t)row*512 + kt + c4*4];
            ushort4 pk = { f2bits(v.x), f2bits(v.y), f2bits(v.z), f2bits(v.w) };
            *(ushort4*)&Bs[row*40 + c4*4] = pk;
        }
        __syncthreads();
        bf16x8 af[4], bfr[8];
        #pragma unroll
        for (int mi = 0; mi < 4; mi++)
            af[mi] = *(const bf16x8*)&As[(mi*16 + l16)*40 + quad*8];
        #pragma unroll
        for (int ni = 0; ni < 8; ni++)
            bfr[ni] = *(const bf16x8*)&Bs[(wave*128 + ni*16 + l16)*40 + quad*8];
        #pragma unroll
        for (int mi = 0; mi < 4; mi++)
            #pragma unroll
            for (int ni = 0; ni < 8; ni++)
                acc[mi][ni] = __builtin_amdgcn_mfma_f32_16x16x32_bf16(af[mi], bfr[ni], acc[mi][ni], 0, 0, 0);
        __syncthreads();
    }
    #pragma unroll
    for (int mi = 0; mi < 4; mi++) {
        #pragma unroll
        for (int rr = 0; rr < 4; rr++) {
            int rl = mi*16 + quad*4 + rr;
            int row = M0 + rl;
            int bb = row / 400;
            float covv = cov[row];
            float psum = 0.f;
            #pragma unroll
            for (int ni = 0; ni < 8; ni++) {
                int d = wave*128 + ni*16 + l16;
                float arg = acc[mi][ni][rr] + dec[bb*512 + d] + covv * wc[d] + bc[d];
                psum += vv[d] * tanhf(arg);
            }
            psum += __shfl_xor(psum, 1);
            psum += __shfl_xor(psum, 2);
            psum += __shfl_xor(psum, 4);
            psum += __shfl_xor(psum, 8);
            if (l16 == 0) part[wave][rl] = psum;
        }
    }
    __syncthreads();
    if (t < 64) e_t[M0 + t] = part[0][t] + part[1][t] + part[2][t] + part[3][t];
}

// ---------------- K4: masked softmax over S + a_t + next_coverage (fp32 out) ----------------
__global__ void k_softmax_s(const float* e_t, const int* mask, const float* cov,
                            float* a_ws, float* o_at, float* o_cov)
{
    int b = blockIdx.x, t = threadIdx.x;
    __shared__ float red[256];
    __shared__ float vals[400];
    float m = -1e30f;
    for (int s = t; s < 400; s += 256) {
        float v = (mask[b*400+s] == 0) ? -1e30f : e_t[b*400+s];
        vals[s] = v;
        m = fmaxf(m, v);
    }
    red[t] = m; __syncthreads();
    for (int o = 128; o > 0; o >>= 1) { if (t < o) red[t] = fmaxf(red[t], red[t+o]); __syncthreads(); }
    m = red[0]; __syncthreads();
    float sum = 0.f;
    for (int s = t; s < 400; s += 256) { float e = __expf(vals[s]-m); vals[s] = e; sum += e; }
    red[t] = sum; __syncthreads();
    for (int o = 128; o > 0; o >>= 1) { if (t < o) red[t] += red[t+o]; __syncthreads(); }
    float inv = 1.f / red[0];
    for (int s = t; s < 400; s += 256) {
        float a = vals[s] * inv;
        a_ws[b*400+s] = a;
        o_at[b*400+s] = a;
        o_cov[b*400+s] = cov[b*400+s] + a;
    }
}

// ---------------- K5: ctx = sum_s a[s] * enc[b,s,:] (fp32) ----------------
__global__ void k_ctx(const float* a_ws, const float* enc, float* ctx_ws)
{
    int b = blockIdx.x, t = threadIdx.x;
    int s0 = blockIdx.y * 100;
    float acc0 = 0.f, acc1 = 0.f;
    for (int s = s0; s < s0+100; s++) {
        float a = a_ws[b*400+s];
        const float* er = enc + ((size_t)b*400 + s)*512;
        float2 v = *(const float2*)&er[2*t];
        acc0 += a * v.x;
        acc1 += a * v.y;
    }
    atomicAdd(&ctx_ws[b*512 + 2*t],     acc0);
    atomicAdd(&ctx_ws[b*512 + 2*t + 1], acc1);
}

// ---------------- K6: gen_p + out1 = relu(W1 @ [h,ctx] + b1) ----------------
__global__ void k_small2(const float* ctx_ws, const float* status, const float* x_ws,
                         const float* gp_wh, const float* gp_bh,
                         const float* gp_ws_, const float* gp_bs,
                         const float* gp_wx, const float* gp_bx,
                         const float* w1, const float* b1,
                         float* o_ctx, float* o_gp,
                         float* gp_v, u16* out1)
{
    int b = blockIdx.x, t = threadIdx.x;
    __shared__ float feat[768];   // [h_t(256), ctx(512)]
    __shared__ float red[256];
    feat[t] = status[b*512+t];
    for (int i = t; i < 512; i += 256) {
        float c = ctx_ws[b*512+i];
        feat[256+i] = c;
        o_ctx[b*512+i] = c;
    }
    __syncthreads();
    float p = 0.f;
    for (int k = t; k < 512; k += 256) {
        p += gp_wh[k]  * feat[256+k];
        p += gp_ws_[k] * status[b*512+k];
    }
    if (t < 128) p += gp_wx[t] * x_ws[b*128+t];
    red[t] = p; __syncthreads();
    for (int o = 128; o > 0; o >>= 1) { if (t < o) red[t] += red[t+o]; __syncthreads(); }
    if (t == 0) {
        float gp = sigm(red[0] + gp_bh[0] + gp_bs[0] + gp_bx[0]);
        gp_v[b] = gp; o_gp[b] = gp;
    }
    __syncthreads();
    {
        float s = b1[t];
        const float* wr = w1 + t*768;
        for (int k = 0; k < 768; k++) s += wr[k] * feat[k];
        out1[b*256+t] = f2bits(fmaxf(s, 0.f));
    }
}

// ---------------- K7: logits = out1 @ w2^T + b2 (MFMA) -> fp32 into d_out final region ----------------
__global__ __launch_bounds__(256) void k_logits(const u16* out1, const float* w2,
                                                const float* b2, float* o_fin)
{
    const int N0 = blockIdx.x * 64;
    int t = threadIdx.x, wave = t >> 6, lane = t & 63, quad = lane >> 4, l16 = lane & 15;
    __shared__ __align__(16) u16 As[128*40];
    __shared__ __align__(16) u16 Bs[64*40];
    f32x4 acc[2][4] = {};
    for (int kt = 0; kt < 256; kt += 32) {
        #pragma unroll
        for (int j = 0; j < 2; j++) {           // A: 128 rows x 32 k (bf16), uint4 = 8 u16
            int gi = j*256 + t;
            int row = gi >> 2, c = gi & 3;
            *(uint4*)&As[row*40 + c*8] = *(const uint4*)&out1[row*256 + kt + c*8];
        }
        #pragma unroll
        for (int j = 0; j < 2; j++) {           // B: 64 cols x 32 k (fp32 -> bf16)
            int gi = j*256 + t;
            int col = gi >> 3, c4 = gi & 7;
            int n = N0 + col;
            float4 v = (n < V_) ? *(const float4*)&w2[(size_t)n*256 + kt + c4*4]
                                : make_float4(0.f,0.f,0.f,0.f);
            ushort4 pk = { f2bits(v.x), f2bits(v.y), f2bits(v.z), f2bits(v.w) };
            *(ushort4*)&Bs[col*40 + c4*4] = pk;
        }
        __syncthreads();
        bf16x8 af[2], bfr[4];
        #pragma unroll
        for (int mi = 0; mi < 2; mi++)
            af[mi] = *(const bf16x8*)&As[(wave*32 + mi*16 + l16)*40 + quad*8];
        #pragma unroll
        for (int ni = 0; ni < 4; ni++)
            bfr[ni] = *(const bf16x8*)&Bs[(ni*16 + l16)*40 + quad*8];
        #pragma unroll
        for (int mi = 0; mi < 2; mi++)
            #pragma unroll
            for (int ni = 0; ni < 4; ni++)
                acc[mi][ni] = __builtin_amdgcn_mfma_f32_16x16x32_bf16(af[mi], bfr[ni], acc[mi][ni], 0, 0, 0);
        __syncthreads();
    }
    #pragma unroll
    for (int ni = 0; ni < 4; ni++) {
        int n = N0 + ni*16 + l16;
        if (n < V_) {
            float bias = b2[n];
            #pragma unroll
            for (int mi = 0; mi < 2; mi++) {
                #pragma unroll
                for (int rr = 0; rr < 4; rr++) {
                    int row = wave*32 + mi*16 + quad*4 + rr;
                    o_fin[(size_t)row*VO_ + n] = acc[mi][ni][rr] + bias;
                }
            }
        }
    }
}

// ---------------- K8: per-row online max + sumexp over V (fp32 logits) ----------------
__global__ void k_rowstats(const float* o_fin, float* rmax, float* rsum)
{
    int b = blockIdx.x, t = threadIdx.x;
    float m = -1e30f, s = 0.f;
    const float* lr = o_fin + (size_t)b*VO_;
    for (int i = t; i < V_; i += 256) {
        float x = lr[i];
        if (x > m) { s = s * __expf(m - x) + 1.f; m = x; }
        else       { s += __expf(x - m); }
    }
    __shared__ float ms[256], ss[256];
    ms[t] = m; ss[t] = s; __syncthreads();
    for (int o = 128; o > 0; o >>= 1) {
        if (t < o) {
            float m2 = fmaxf(ms[t], ms[t+o]);
            ss[t] = ss[t]*__expf(ms[t]-m2) + ss[t+o]*__expf(ms[t+o]-m2);
            ms[t] = m2;
        }
        __syncthreads();
    }
    if (t == 0) { rmax[b] = ms[0]; rsum[b] = ss[0]; }
}

// ---------------- K9a: in-place normalize + OOV tail (fp32) ----------------
__global__ void k_norm(float* o_fin, const float* rmax, const float* rsum,
                       const float* gp, const float* oovz)
{
    int b = blockIdx.y;
    int i = blockIdx.x*256 + threadIdx.x;
    if (i >= VO_) return;
    size_t idx = (size_t)b*VO_ + i;
    if (i < V_) {
        float l = o_fin[idx];
        o_fin[idx] = __expf(l - rmax[b]) * (gp[b] / rsum[b]);
    } else {
        o_fin[idx] = oovz[b*OOV_ + (i - V_)];
    }
}

// ---------------- K9b: pointer scatter-add (native fp32 atomics) ----------------
__global__ void k_scatter(const int* eoov, const float* a_ws, const float* gp,
                          float* o_fin)
{
    int b = blockIdx.x, t = threadIdx.x;
    float w = 1.f - gp[b];
    for (int s = t; s < 400; s += 256) {
        int idx = eoov[b*400+s];
        float v = a_ws[b*400+s] * w;
        atomicAdd(&o_fin[(size_t)b*VO_ + idx], v);
    }
}

extern "C" void kernel_launch(void* const* d_in, const int* in_sizes, int n_in,
                              void* d_out, int out_size, void* d_ws, size_t ws_size,
                              hipStream_t stream)
{
    const int*   tok  = (const int*)d_in[0];
    const float* h0   = (const float*)d_in[1];
    const float* c0   = (const float*)d_in[2];
    const float* enc  = (const float*)d_in[3];
    const int*   mask = (const int*)d_in[4];
    const float* ctxv = (const float*)d_in[5];
    const float* oovz = (const float*)d_in[6];
    const int*   eoov = (const int*)d_in[7];
    const float* cov  = (const float*)d_in[8];
    const float* emb  = (const float*)d_in[9];
    const float* Wi   = (const float*)d_in[10];
    const float* bi   = (const float*)d_in[11];
    const float* W_ih = (const float*)d_in[12];
    const float* W_hh = (const float*)d_in[13];
    const float* b_ih = (const float*)d_in[14];
    const float* b_hh = (const float*)d_in[15];
    const float* awh  = (const float*)d_in[16];
    const float* aws  = (const float*)d_in[17];
    const float* awc  = (const float*)d_in[18];
    const float* abc  = (const float*)d_in[19];
    const float* av   = (const float*)d_in[20];
    const float* gp_wh= (const float*)d_in[21];
    const float* gp_bh= (const float*)d_in[22];
    const float* gp_ws= (const float*)d_in[23];
    const float* gp_bs= (const float*)d_in[24];
    const float* gp_wx= (const float*)d_in[25];
    const float* gp_bx= (const float*)d_in[26];
    const float* w1   = (const float*)d_in[27];
    const float* b1   = (const float*)d_in[28];
    const float* w2   = (const float*)d_in[29];
    const float* b2   = (const float*)d_in[30];

    // compact workspace (~1.33 MB)
    char* ws = (char*)d_ws;
    float* ctx_ws = (float*)(ws + 0);          // 65536 f32 (zeroed, atomic)
    float* e_t    = (float*)(ws + 262144);     // 51200 f32 (written whole)
    float* status = (float*)(ws + 466944);     // 128*512
    float* x_ws   = (float*)(ws + 729088);     // 128*128
    float* dec_ws = (float*)(ws + 794624);     // 128*512
    float* a_ws   = (float*)(ws + 1056768);    // 128*400
    float* gp_v   = (float*)(ws + 1261568);    // 128
    float* rmax   = (float*)(ws + 1262080);    // 128
    float* rsum   = (float*)(ws + 1262592);    // 128
    u16*   out1   = (u16*)  (ws + 1263104);    // 128*256 bf16

    float* out   = (float*)d_out;              // fp32 outputs (reference dtype)
    float* o_fin = out;                        // 128*50050
    float* o_ht  = out + 6406400;
    float* o_ct  = out + 6439168;
    float* o_ctx = out + 6471936;
    float* o_at  = out + 6537472;
    float* o_gp  = out + 6588672;
    float* o_cov = out + 6588800;

    k_init<<<dim3(256), 256, 0, stream>>>(ctx_ws, 65536);
    k_small1<<<dim3(128), 256, 0, stream>>>(tok, emb, ctxv, h0, c0, Wi, bi,
                                            W_ih, W_hh, b_ih, b_hh, aws,
                                            o_ht, o_ct, status, x_ws, dec_ws);
    k_attn<<<dim3(800), 256, 0, stream>>>(enc, awh, dec_ws, cov, awc, abc, av, e_t);
    k_softmax_s<<<dim3(128), 256, 0, stream>>>(e_t, mask, cov, a_ws, o_at, o_cov);
    k_ctx<<<dim3(128, 4), 256, 0, stream>>>(a_ws, enc, ctx_ws);
    k_small2<<<dim3(128), 256, 0, stream>>>(ctx_ws, status, x_ws,
                                            gp_wh, gp_bh, gp_ws, gp_bs, gp_wx, gp_bx,
                                            w1, b1, o_ctx, o_gp, gp_v, out1);
    k_logits<<<dim3(782), 256, 0, stream>>>(out1, w2, b2, o_fin);
    k_rowstats<<<dim3(128), 256, 0, stream>>>(o_fin, rmax, rsum);
    k_norm<<<dim3(196, 128), 256, 0, stream>>>(o_fin, rmax, rsum, gp_v, oovz);
    k_scatter<<<dim3(128), 256, 0, stream>>>(eoov, a_ws, gp_v, o_fin);
}

// Round 7
// 696.792 us; speedup vs baseline: 1.0652x; 1.0652x over previous
//
#include <hip/hip_runtime.h>
#include <hip/hip_bf16.h>
#include <string.h>

// Sizes
#define V_    50000
#define VO_   50050
#define E_    128
#define H_    256
#define S_    400
#define B_    128
#define OOV_  50

typedef __bf16  bf16x8 __attribute__((ext_vector_type(8)));
typedef float   f32x4  __attribute__((ext_vector_type(4)));
typedef unsigned short u16;
typedef unsigned int   u32;

__device__ __forceinline__ float sigm(float x){ return 1.f/(1.f+__expf(-x)); }
__device__ __forceinline__ u16 f2bits(float f){ __hip_bfloat16 h = __float2bfloat16(f); u16 b; memcpy(&b, &h, 2); return b; }

// async global->LDS DMA, 16 B per lane, LDS dst = wave-uniform base + lane*16
#define ASYNC_COPY16(g, l) \
    __builtin_amdgcn_global_load_lds((const __attribute__((address_space(1))) u32*)(g), \
                                     (__attribute__((address_space(3))) u32*)(l), 16, 0, 0)

// ---------------- K0: zero ctx accumulator ----------------
__global__ void k_init(float* p, int n){
    int i = blockIdx.x*256 + threadIdx.x;
    if (i < n) p[i] = 0.f;
}

// ---------------- K0b: convert att_wh (512x512 fp32) -> bf16 once ----------------
__global__ void k_cvt(const float* src, u16* dst){
    int i = (blockIdx.x*256 + threadIdx.x) * 4;   // 262144 elements / 1024 threads-work
    float4 v = *(const float4*)&src[i];
    ushort4 pk = { f2bits(v.x), f2bits(v.y), f2bits(v.z), f2bits(v.w) };
    *(ushort4*)&dst[i] = pk;
}

// ---------------- K1: embed + x + LSTM cell + dec_feat (all fp32) ----------------
__global__ void k_small1(const int* tok, const float* emb, const float* ctxv,
                         const float* h0, const float* c0,
                         const float* Wi, const float* bi,
                         const float* W_ih, const float* W_hh,
                         const float* b_ih, const float* b_hh,
                         const float* aws,
                         float* o_ht, float* o_ct,
                         float* ws_status, float* ws_x, float* ws_dec)
{
    int b = blockIdx.x, t = threadIdx.x;
    __shared__ float in_vec[640];   // [context_vec(512), embed(128)]
    __shared__ float h0s[256];
    __shared__ float xs[128];
    __shared__ float xred[256];
    __shared__ float gates[1024];
    __shared__ float st[512];
    for (int i = t; i < 512; i += 256) in_vec[i] = ctxv[b*512+i];
    int tk = tok[b];
    if (t < 128) in_vec[512+t] = emb[tk*128+t];
    h0s[t] = h0[b*256+t];
    __syncthreads();
    {   // x projection: 2 threads per row, split K 640 = 2*320
        int row = t >> 1, half = t & 1;
        float s = 0.f;
        const float* wr = Wi + row*640 + half*320;
        const float* iv = in_vec + half*320;
        for (int k = 0; k < 320; k++) s += wr[k] * iv[k];
        xred[t] = s;
    }
    __syncthreads();
    if (t < 128) {
        float s = xred[2*t] + xred[2*t+1] + bi[t];
        xs[t] = s; ws_x[b*128+t] = s;
    }
    __syncthreads();
    for (int g = t; g < 1024; g += 256) {
        float s = b_ih[g] + b_hh[g];
        const float* wr = W_ih + g*128;
        for (int k = 0; k < 128; k++) s += wr[k] * xs[k];
        const float* hr = W_hh + g*256;
        for (int k = 0; k < 256; k++) s += hr[k] * h0s[k];
        gates[g] = s;
    }
    __syncthreads();
    {   // torch gate order i,f,g,o
        float ig = sigm(gates[t]);
        float fg = sigm(gates[256+t]);
        float gg = tanhf(gates[512+t]);
        float og = sigm(gates[768+t]);
        float c  = fg * c0[b*256+t] + ig * gg;
        float h  = og * tanhf(c);
        st[t] = h; st[256+t] = c;
        o_ht[b*256+t] = h; o_ct[b*256+t] = c;
        ws_status[b*512+t] = h; ws_status[b*512+256+t] = c;
    }
    __syncthreads();
    for (int d = t; d < 512; d += 256) {
        float s = 0.f;
        const float* wr = aws + d*512;
        for (int k = 0; k < 512; k++) s += wr[k] * st[k];
        ws_dec[b*512+d] = s;
    }
}

// ---------------- K3: enc_feat GEMM fused tanh+dot(att_v), m97-style staging ----------------
// Block: 64 rows (M) x full N=512; 4 waves each N=128. B (wh bf16) via global_load_lds.
__global__ __launch_bounds__(256) void k_attn(
    const float* enc, const u16* whb, const float* dec, const float* cov,
    const float* wc, const float* bc, const float* vv, float* e_t)
{
    const int M0 = blockIdx.x * 64;
    int t = threadIdx.x;
    int wave = t >> 6, lane = t & 63, quad = lane >> 4, l16 = lane & 15;
    __shared__ __align__(16) u16 As[64*40];     // padded stride 40
    __shared__ __align__(16) u16 Bs[512*32];    // contiguous stride 32 (DMA layout)
    __shared__ float part[4][64];
    f32x4 acc[4][8] = {};
    const int arow = t >> 2, ac8 = (t & 3) * 8;             // A: 4 thr/row, 8 k each
    const int brow = wave*128 + (lane >> 2);                // B DMA row base (j adds 16)
    const int bkk  = (lane & 3) * 8;
    for (int kt = 0; kt < 512; kt += 32) {
        // B: 512x32 bf16 via DMA (8 instrs/thread, 1 KB per wave-instr)
        #pragma unroll
        for (int j = 0; j < 8; j++) {
            const u16* src = whb + (size_t)(brow + j*16)*512 + kt + bkk;
            ASYNC_COPY16(src, &Bs[wave*4096 + j*512]);
        }
        // A: 64x32 fp32 -> bf16 (8 elem/thread)
        {
            const float* ap = &enc[(size_t)(M0 + arow)*512 + kt + ac8];
            float4 v0 = *(const float4*)ap;
            float4 v1 = *(const float4*)(ap + 4);
            ushort4 p0 = { f2bits(v0.x), f2bits(v0.y), f2bits(v0.z), f2bits(v0.w) };
            ushort4 p1 = { f2bits(v1.x), f2bits(v1.y), f2bits(v1.z), f2bits(v1.w) };
            *(ushort4*)&As[arow*40 + ac8]     = p0;
            *(ushort4*)&As[arow*40 + ac8 + 4] = p1;
        }
        __syncthreads();
        bf16x8 af[4], bfr[8];
        #pragma unroll
        for (int mi = 0; mi < 4; mi++)
            af[mi] = *(const bf16x8*)&As[(mi*16 + l16)*40 + quad*8];
        #pragma unroll
        for (int ni = 0; ni < 8; ni++)
            bfr[ni] = *(const bf16x8*)&Bs[(wave*128 + ni*16 + l16)*32 + quad*8];
        #pragma unroll
        for (int mi = 0; mi < 4; mi++)
            #pragma unroll
            for (int ni = 0; ni < 8; ni++)
                acc[mi][ni] = __builtin_amdgcn_mfma_f32_16x16x32_bf16(af[mi], bfr[ni], acc[mi][ni], 0, 0, 0);
        __syncthreads();
    }
    #pragma unroll
    for (int mi = 0; mi < 4; mi++) {
        #pragma unroll
        for (int rr = 0; rr < 4; rr++) {
            int rl = mi*16 + quad*4 + rr;
            int row = M0 + rl;
            int bb = row / 400;
            float covv = cov[row];
            float psum = 0.f;
            #pragma unroll
            for (int ni = 0; ni < 8; ni++) {
                int d = wave*128 + ni*16 + l16;
                float arg = acc[mi][ni][rr] + dec[bb*512 + d] + covv * wc[d] + bc[d];
                psum += vv[d] * tanhf(arg);
            }
            psum += __shfl_xor(psum, 1);
            psum += __shfl_xor(psum, 2);
            psum += __shfl_xor(psum, 4);
            psum += __shfl_xor(psum, 8);
            if (l16 == 0) part[wave][rl] = psum;
        }
    }
    __syncthreads();
    if (t < 64) e_t[M0 + t] = part[0][t] + part[1][t] + part[2][t] + part[3][t];
}

// ---------------- K4: masked softmax over S + a_t + next_coverage (fp32 out) ----------------
__global__ void k_softmax_s(const float* e_t, const int* mask, const float* cov,
                            float* a_ws, float* o_at, float* o_cov)
{
    int b = blockIdx.x, t = threadIdx.x;
    __shared__ float red[256];
    __shared__ float vals[400];
    float m = -1e30f;
    for (int s = t; s < 400; s += 256) {
        float v = (mask[b*400+s] == 0) ? -1e30f : e_t[b*400+s];
        vals[s] = v;
        m = fmaxf(m, v);
    }
    red[t] = m; __syncthreads();
    for (int o = 128; o > 0; o >>= 1) { if (t < o) red[t] = fmaxf(red[t], red[t+o]); __syncthreads(); }
    m = red[0]; __syncthreads();
    float sum = 0.f;
    for (int s = t; s < 400; s += 256) { float e = __expf(vals[s]-m); vals[s] = e; sum += e; }
    red[t] = sum; __syncthreads();
    for (int o = 128; o > 0; o >>= 1) { if (t < o) red[t] += red[t+o]; __syncthreads(); }
    float inv = 1.f / red[0];
    for (int s = t; s < 400; s += 256) {
        float a = vals[s] * inv;
        a_ws[b*400+s] = a;
        o_at[b*400+s] = a;
        o_cov[b*400+s] = cov[b*400+s] + a;
    }
}

// ---------------- K5: ctx = sum_s a[s] * enc[b,s,:] (fp32), grid (128,8) ----------------
__global__ void k_ctx(const float* a_ws, const float* enc, float* ctx_ws)
{
    int b = blockIdx.x, t = threadIdx.x;
    int s0 = blockIdx.y * 50;
    float acc0 = 0.f, acc1 = 0.f;
    for (int s = s0; s < s0+50; s++) {
        float a = a_ws[b*400+s];
        const float* er = enc + ((size_t)b*400 + s)*512;
        float2 v = *(const float2*)&er[2*t];
        acc0 += a * v.x;
        acc1 += a * v.y;
    }
    atomicAdd(&ctx_ws[b*512 + 2*t],     acc0);
    atomicAdd(&ctx_ws[b*512 + 2*t + 1], acc1);
}

// ---------------- K6: gen_p + out1 = relu(W1 @ [h,ctx] + b1) ----------------
__global__ void k_small2(const float* ctx_ws, const float* status, const float* x_ws,
                         const float* gp_wh, const float* gp_bh,
                         const float* gp_ws_, const float* gp_bs,
                         const float* gp_wx, const float* gp_bx,
                         const float* w1, const float* b1,
                         float* o_ctx, float* o_gp,
                         float* gp_v, u16* out1)
{
    int b = blockIdx.x, t = threadIdx.x;
    __shared__ float feat[768];   // [h_t(256), ctx(512)]
    __shared__ float red[256];
    feat[t] = status[b*512+t];
    for (int i = t; i < 512; i += 256) {
        float c = ctx_ws[b*512+i];
        feat[256+i] = c;
        o_ctx[b*512+i] = c;
    }
    __syncthreads();
    float p = 0.f;
    for (int k = t; k < 512; k += 256) {
        p += gp_wh[k]  * feat[256+k];
        p += gp_ws_[k] * status[b*512+k];
    }
    if (t < 128) p += gp_wx[t] * x_ws[b*128+t];
    red[t] = p; __syncthreads();
    for (int o = 128; o > 0; o >>= 1) { if (t < o) red[t] += red[t+o]; __syncthreads(); }
    if (t == 0) {
        float gp = sigm(red[0] + gp_bh[0] + gp_bs[0] + gp_bx[0]);
        gp_v[b] = gp; o_gp[b] = gp;
    }
    __syncthreads();
    {
        float s = b1[t];
        const float* wr = w1 + t*768;
        for (int k = 0; k < 768; k++) s += wr[k] * feat[k];
        out1[b*256+t] = f2bits(fmaxf(s, 0.f));
    }
}

// ---------------- K7: logits = out1 @ w2^T + b2 (MFMA) -> fp32 into d_out ----------------
__global__ __launch_bounds__(256) void k_logits(const u16* out1, const float* w2,
                                                const float* b2, float* o_fin)
{
    const int N0 = blockIdx.x * 64;
    int t = threadIdx.x, wave = t >> 6, lane = t & 63, quad = lane >> 4, l16 = lane & 15;
    __shared__ __align__(16) u16 As[128*40];
    __shared__ __align__(16) u16 Bs[64*40];
    f32x4 acc[2][4] = {};
    for (int kt = 0; kt < 256; kt += 32) {
        #pragma unroll
        for (int j = 0; j < 2; j++) {           // A: 128 rows x 32 k (bf16), uint4 = 8 u16
            int gi = j*256 + t;
            int row = gi >> 2, c = gi & 3;
            *(uint4*)&As[row*40 + c*8] = *(const uint4*)&out1[row*256 + kt + c*8];
        }
        #pragma unroll
        for (int j = 0; j < 2; j++) {           // B: 64 cols x 32 k (fp32 -> bf16)
            int gi = j*256 + t;
            int col = gi >> 3, c4 = gi & 7;
            int n = N0 + col;
            float4 v = (n < V_) ? *(const float4*)&w2[(size_t)n*256 + kt + c4*4]
                                : make_float4(0.f,0.f,0.f,0.f);
            ushort4 pk = { f2bits(v.x), f2bits(v.y), f2bits(v.z), f2bits(v.w) };
            *(ushort4*)&Bs[col*40 + c4*4] = pk;
        }
        __syncthreads();
        bf16x8 af[2], bfr[4];
        #pragma unroll
        for (int mi = 0; mi < 2; mi++)
            af[mi] = *(const bf16x8*)&As[(wave*32 + mi*16 + l16)*40 + quad*8];
        #pragma unroll
        for (int ni = 0; ni < 4; ni++)
            bfr[ni] = *(const bf16x8*)&Bs[(ni*16 + l16)*40 + quad*8];
        #pragma unroll
        for (int mi = 0; mi < 2; mi++)
            #pragma unroll
            for (int ni = 0; ni < 4; ni++)
                acc[mi][ni] = __builtin_amdgcn_mfma_f32_16x16x32_bf16(af[mi], bfr[ni], acc[mi][ni], 0, 0, 0);
        __syncthreads();
    }
    #pragma unroll
    for (int ni = 0; ni < 4; ni++) {
        int n = N0 + ni*16 + l16;
        if (n < V_) {
            float bias = b2[n];
            #pragma unroll
            for (int mi = 0; mi < 2; mi++) {
                #pragma unroll
                for (int rr = 0; rr < 4; rr++) {
                    int row = wave*32 + mi*16 + quad*4 + rr;
                    o_fin[(size_t)row*VO_ + n] = acc[mi][ni][rr] + bias;
                }
            }
        }
    }
}

// ---------------- K8: per-row online max + sumexp over V (fp32 logits) ----------------
__global__ void k_rowstats(const float* o_fin, float* rmax, float* rsum)
{
    int b = blockIdx.x, t = threadIdx.x;
    float m = -1e30f, s = 0.f;
    const float* lr = o_fin + (size_t)b*VO_;
    for (int i = t; i < V_; i += 256) {
        float x = lr[i];
        if (x > m) { s = s * __expf(m - x) + 1.f; m = x; }
        else       { s += __expf(x - m); }
    }
    __shared__ float ms[256], ss[256];
    ms[t] = m; ss[t] = s; __syncthreads();
    for (int o = 128; o > 0; o >>= 1) {
        if (t < o) {
            float m2 = fmaxf(ms[t], ms[t+o]);
            ss[t] = ss[t]*__expf(ms[t]-m2) + ss[t+o]*__expf(ms[t+o]-m2);
            ms[t] = m2;
        }
        __syncthreads();
    }
    if (t == 0) { rmax[b] = ms[0]; rsum[b] = ss[0]; }
}

// ---------------- K9a: in-place normalize + OOV tail (fp32) ----------------
__global__ void k_norm(float* o_fin, const float* rmax, const float* rsum,
                       const float* gp, const float* oovz)
{
    int b = blockIdx.y;
    int i = blockIdx.x*256 + threadIdx.x;
    if (i >= VO_) return;
    size_t idx = (size_t)b*VO_ + i;
    if (i < V_) {
        float l = o_fin[idx];
        o_fin[idx] = __expf(l - rmax[b]) * (gp[b] / rsum[b]);
    } else {
        o_fin[idx] = oovz[b*OOV_ + (i - V_)];
    }
}

// ---------------- K9b: pointer scatter-add (native fp32 atomics) ----------------
__global__ void k_scatter(const int* eoov, const float* a_ws, const float* gp,
                          float* o_fin)
{
    int b = blockIdx.x, t = threadIdx.x;
    float w = 1.f - gp[b];
    for (int s = t; s < 400; s += 256) {
        int idx = eoov[b*400+s];
        float v = a_ws[b*400+s] * w;
        atomicAdd(&o_fin[(size_t)b*VO_ + idx], v);
    }
}

extern "C" void kernel_launch(void* const* d_in, const int* in_sizes, int n_in,
                              void* d_out, int out_size, void* d_ws, size_t ws_size,
                              hipStream_t stream)
{
    const int*   tok  = (const int*)d_in[0];
    const float* h0   = (const float*)d_in[1];
    const float* c0   = (const float*)d_in[2];
    const float* enc  = (const float*)d_in[3];
    const int*   mask = (const int*)d_in[4];
    const float* ctxv = (const float*)d_in[5];
    const float* oovz = (const float*)d_in[6];
    const int*   eoov = (const int*)d_in[7];
    const float* cov  = (const float*)d_in[8];
    const float* emb  = (const float*)d_in[9];
    const float* Wi   = (const float*)d_in[10];
    const float* bi   = (const float*)d_in[11];
    const float* W_ih = (const float*)d_in[12];
    const float* W_hh = (const float*)d_in[13];
    const float* b_ih = (const float*)d_in[14];
    const float* b_hh = (const float*)d_in[15];
    const float* awh  = (const float*)d_in[16];
    const float* aws  = (const float*)d_in[17];
    const float* awc  = (const float*)d_in[18];
    const float* abc  = (const float*)d_in[19];
    const float* av   = (const float*)d_in[20];
    const float* gp_wh= (const float*)d_in[21];
    const float* gp_bh= (const float*)d_in[22];
    const float* gp_ws= (const float*)d_in[23];
    const float* gp_bs= (const float*)d_in[24];
    const float* gp_wx= (const float*)d_in[25];
    const float* gp_bx= (const float*)d_in[26];
    const float* w1   = (const float*)d_in[27];
    const float* b1   = (const float*)d_in[28];
    const float* w2   = (const float*)d_in[29];
    const float* b2   = (const float*)d_in[30];

    // compact workspace (~1.85 MB)
    char* ws = (char*)d_ws;
    float* ctx_ws = (float*)(ws + 0);          // 65536 f32 (zeroed, atomic)
    float* e_t    = (float*)(ws + 262144);     // 51200 f32 (written whole)
    float* status = (float*)(ws + 466944);     // 128*512
    float* x_ws   = (float*)(ws + 729088);     // 128*128
    float* dec_ws = (float*)(ws + 794624);     // 128*512
    float* a_ws   = (float*)(ws + 1056768);    // 128*400
    float* gp_v   = (float*)(ws + 1261568);    // 128
    float* rmax   = (float*)(ws + 1262080);    // 128
    float* rsum   = (float*)(ws + 1262592);    // 128
    u16*   out1   = (u16*)  (ws + 1263104);    // 128*256 bf16 -> 1328640
    u16*   wh_bf  = (u16*)  (ws + 1328640);    // 512*512 bf16 -> 1852928

    float* out   = (float*)d_out;              // fp32 outputs (reference dtype)
    float* o_fin = out;                        // 128*50050
    float* o_ht  = out + 6406400;
    float* o_ct  = out + 6439168;
    float* o_ctx = out + 6471936;
    float* o_at  = out + 6537472;
    float* o_gp  = out + 6588672;
    float* o_cov = out + 6588800;

    k_init<<<dim3(256), 256, 0, stream>>>(ctx_ws, 65536);
    k_cvt<<<dim3(256), 256, 0, stream>>>(awh, wh_bf);
    k_small1<<<dim3(128), 256, 0, stream>>>(tok, emb, ctxv, h0, c0, Wi, bi,
                                            W_ih, W_hh, b_ih, b_hh, aws,
                                            o_ht, o_ct, status, x_ws, dec_ws);
    k_attn<<<dim3(800), 256, 0, stream>>>(enc, wh_bf, dec_ws, cov, awc, abc, av, e_t);
    k_softmax_s<<<dim3(128), 256, 0, stream>>>(e_t, mask, cov, a_ws, o_at, o_cov);
    k_ctx<<<dim3(128, 8), 256, 0, stream>>>(a_ws, enc, ctx_ws);
    k_small2<<<dim3(128), 256, 0, stream>>>(ctx_ws, status, x_ws,
                                            gp_wh, gp_bh, gp_ws, gp_bs, gp_wx, gp_bx,
                                            w1, b1, o_ctx, o_gp, gp_v, out1);
    k_logits<<<dim3(782), 256, 0, stream>>>(out1, w2, b2, o_fin);
    k_rowstats<<<dim3(128), 256, 0, stream>>>(o_fin, rmax, rsum);
    k_norm<<<dim3(196, 128), 256, 0, stream>>>(o_fin, rmax, rsum, gp_v, oovz);
    k_scatter<<<dim3(128), 256, 0, stream>>>(eoov, a_ws, gp_v, o_fin);
}

// Round 8
// 542.284 us; speedup vs baseline: 1.3687x; 1.2849x over previous
//
#include <hip/hip_runtime.h>
#include <hip/hip_bf16.h>
#include <string.h>

// Sizes
#define V_    50000
#define VO_   50050
#define E_    128
#define H_    256
#define S_    400
#define B_    128
#define OOV_  50

typedef __bf16  bf16x8 __attribute__((ext_vector_type(8)));
typedef float   f32x4  __attribute__((ext_vector_type(4)));
typedef unsigned short u16;
typedef unsigned int   u32;

__device__ __forceinline__ float sigm(float x){ return 1.f/(1.f+__expf(-x)); }
__device__ __forceinline__ float tanh_fast(float x){ float e = __expf(2.f*x); return 1.f - 2.f/(e+1.f); }
__device__ __forceinline__ u16 f2bits(float f){ __hip_bfloat16 h = __float2bfloat16(f); u16 b; memcpy(&b, &h, 2); return b; }

// async global->LDS DMA, 16 B per lane, LDS dst = wave-uniform base + lane*16
#define ASYNC_COPY16(g, l) \
    __builtin_amdgcn_global_load_lds((const __attribute__((address_space(1))) u32*)(g), \
                                     (__attribute__((address_space(3))) u32*)(l), 16, 0, 0)

// ---------------- K0: zero ctx accumulator + e_t (contiguous 116736 floats) ----------------
__global__ void k_init(float* p, int n){
    int i = blockIdx.x*256 + threadIdx.x;
    if (i < n) p[i] = 0.f;
}

// ---------------- K0b: convert att_wh (512x512 fp32) -> bf16 once ----------------
__global__ void k_cvt(const float* src, u16* dst){
    int i = (blockIdx.x*256 + threadIdx.x) * 4;
    float4 v = *(const float4*)&src[i];
    ushort4 pk = { f2bits(v.x), f2bits(v.y), f2bits(v.z), f2bits(v.w) };
    *(ushort4*)&dst[i] = pk;
}

// ---------------- K1: embed + x + LSTM cell + dec_feat (all fp32) ----------------
__global__ void k_small1(const int* tok, const float* emb, const float* ctxv,
                         const float* h0, const float* c0,
                         const float* Wi, const float* bi,
                         const float* W_ih, const float* W_hh,
                         const float* b_ih, const float* b_hh,
                         const float* aws,
                         float* o_ht, float* o_ct,
                         float* ws_status, float* ws_x, float* ws_dec)
{
    int b = blockIdx.x, t = threadIdx.x;
    __shared__ float in_vec[640];   // [context_vec(512), embed(128)]
    __shared__ float h0s[256];
    __shared__ float xs[128];
    __shared__ float xred[256];
    __shared__ float gates[1024];
    __shared__ float st[512];
    for (int i = t; i < 512; i += 256) in_vec[i] = ctxv[b*512+i];
    int tk = tok[b];
    if (t < 128) in_vec[512+t] = emb[tk*128+t];
    h0s[t] = h0[b*256+t];
    __syncthreads();
    {   // x projection: 2 threads per row
        int row = t >> 1, half = t & 1;
        float s = 0.f;
        const float* wr = Wi + row*640 + half*320;
        const float* iv = in_vec + half*320;
        for (int k = 0; k < 320; k++) s += wr[k] * iv[k];
        xred[t] = s;
    }
    __syncthreads();
    if (t < 128) {
        float s = xred[2*t] + xred[2*t+1] + bi[t];
        xs[t] = s; ws_x[b*128+t] = s;
    }
    __syncthreads();
    for (int g = t; g < 1024; g += 256) {
        float s = b_ih[g] + b_hh[g];
        const float* wr = W_ih + g*128;
        for (int k = 0; k < 128; k++) s += wr[k] * xs[k];
        const float* hr = W_hh + g*256;
        for (int k = 0; k < 256; k++) s += hr[k] * h0s[k];
        gates[g] = s;
    }
    __syncthreads();
    {   // torch gate order i,f,g,o
        float ig = sigm(gates[t]);
        float fg = sigm(gates[256+t]);
        float gg = tanhf(gates[512+t]);
        float og = sigm(gates[768+t]);
        float c  = fg * c0[b*256+t] + ig * gg;
        float h  = og * tanhf(c);
        st[t] = h; st[256+t] = c;
        o_ht[b*256+t] = h; o_ct[b*256+t] = c;
        ws_status[b*512+t] = h; ws_status[b*512+256+t] = c;
    }
    __syncthreads();
    for (int d = t; d < 512; d += 256) {
        float s = 0.f;
        const float* wr = aws + d*512;
        for (int k = 0; k < 512; k++) s += wr[k] * st[k];
        ws_dec[b*512+d] = s;
    }
}

// ---------------- K3: enc_feat GEMM fused tanh+dot(att_v), occupancy-tuned ----------------
// grid (800, 2): block = 64 rows x 256 cols; 4 waves, each 64x64 (acc = 64 AGPR).
// e_t accumulated via fp32 atomics (2 N-blocks x 4 waves partials per row).
__global__ __launch_bounds__(256, 2) void k_attn(
    const float* enc, const u16* whb, const float* dec, const float* cov,
    const float* wc, const float* bc, const float* vv, float* e_t)
{
    const int M0 = blockIdx.x * 64;
    const int N0 = blockIdx.y * 256;
    int t = threadIdx.x;
    int wave = t >> 6, lane = t & 63, quad = lane >> 4, l16 = lane & 15;
    __shared__ __align__(16) u16 As[64*40];     // padded stride 40
    __shared__ __align__(16) u16 Bs[256*32];    // contiguous stride 32 (DMA layout)
    f32x4 acc[4][4] = {};
    const int arow = t >> 2, ac8 = (t & 3) * 8;             // A: 4 thr/row, 8 k each
    const int brow_l = (lane >> 2);                          // 0..15 within 16-row group
    const int bkk  = (lane & 3) * 8;
    for (int kt = 0; kt < 512; kt += 32) {
        // B: 256 rows x 32 k bf16 via DMA; per wave 4 instrs of 16 rows
        #pragma unroll
        for (int j = 0; j < 4; j++) {
            int rbase = wave*64 + j*16;
            const u16* src = whb + (size_t)(N0 + rbase + brow_l)*512 + kt + bkk;
            ASYNC_COPY16(src, &Bs[rbase*32]);
        }
        // A: 64x32 fp32 -> bf16 (8 elem/thread)
        {
            const float* ap = &enc[(size_t)(M0 + arow)*512 + kt + ac8];
            float4 v0 = *(const float4*)ap;
            float4 v1 = *(const float4*)(ap + 4);
            ushort4 p0 = { f2bits(v0.x), f2bits(v0.y), f2bits(v0.z), f2bits(v0.w) };
            ushort4 p1 = { f2bits(v1.x), f2bits(v1.y), f2bits(v1.z), f2bits(v1.w) };
            *(ushort4*)&As[arow*40 + ac8]     = p0;
            *(ushort4*)&As[arow*40 + ac8 + 4] = p1;
        }
        __syncthreads();
        bf16x8 af[4], bfr[4];
        #pragma unroll
        for (int mi = 0; mi < 4; mi++)
            af[mi] = *(const bf16x8*)&As[(mi*16 + l16)*40 + quad*8];
        #pragma unroll
        for (int ni = 0; ni < 4; ni++)
            bfr[ni] = *(const bf16x8*)&Bs[(wave*64 + ni*16 + l16)*32 + quad*8];
        #pragma unroll
        for (int mi = 0; mi < 4; mi++)
            #pragma unroll
            for (int ni = 0; ni < 4; ni++)
                acc[mi][ni] = __builtin_amdgcn_mfma_f32_16x16x32_bf16(af[mi], bfr[ni], acc[mi][ni], 0, 0, 0);
        __syncthreads();
    }
    // epilogue: partial e over this wave's 64 cols; fast tanh; shfl-reduce 16 lanes; atomic add
    #pragma unroll
    for (int mi = 0; mi < 4; mi++) {
        #pragma unroll
        for (int rr = 0; rr < 4; rr++) {
            int rl = mi*16 + quad*4 + rr;
            int row = M0 + rl;
            int bb = row / 400;
            float covv = cov[row];
            float psum = 0.f;
            #pragma unroll
            for (int ni = 0; ni < 4; ni++) {
                int d = N0 + wave*64 + ni*16 + l16;
                float arg = acc[mi][ni][rr] + dec[bb*512 + d] + covv * wc[d] + bc[d];
                psum += vv[d] * tanh_fast(arg);
            }
            psum += __shfl_xor(psum, 1);
            psum += __shfl_xor(psum, 2);
            psum += __shfl_xor(psum, 4);
            psum += __shfl_xor(psum, 8);
            if (l16 == 0) atomicAdd(&e_t[row], psum);
        }
    }
}

// ---------------- K4: masked softmax over S + a_t + next_coverage (fp32 out) ----------------
__global__ void k_softmax_s(const float* e_t, const int* mask, const float* cov,
                            float* a_ws, float* o_at, float* o_cov)
{
    int b = blockIdx.x, t = threadIdx.x;
    __shared__ float red[256];
    __shared__ float vals[400];
    float m = -1e30f;
    for (int s = t; s < 400; s += 256) {
        float v = (mask[b*400+s] == 0) ? -1e30f : e_t[b*400+s];
        vals[s] = v;
        m = fmaxf(m, v);
    }
    red[t] = m; __syncthreads();
    for (int o = 128; o > 0; o >>= 1) { if (t < o) red[t] = fmaxf(red[t], red[t+o]); __syncthreads(); }
    m = red[0]; __syncthreads();
    float sum = 0.f;
    for (int s = t; s < 400; s += 256) { float e = __expf(vals[s]-m); vals[s] = e; sum += e; }
    red[t] = sum; __syncthreads();
    for (int o = 128; o > 0; o >>= 1) { if (t < o) red[t] += red[t+o]; __syncthreads(); }
    float inv = 1.f / red[0];
    for (int s = t; s < 400; s += 256) {
        float a = vals[s] * inv;
        a_ws[b*400+s] = a;
        o_at[b*400+s] = a;
        o_cov[b*400+s] = cov[b*400+s] + a;
    }
}

// ---------------- K5: ctx = sum_s a[s] * enc[b,s,:] (fp32), grid (128,8) ----------------
__global__ void k_ctx(const float* a_ws, const float* enc, float* ctx_ws)
{
    int b = blockIdx.x, t = threadIdx.x;
    int s0 = blockIdx.y * 50;
    float acc0 = 0.f, acc1 = 0.f;
    for (int s = s0; s < s0+50; s++) {
        float a = a_ws[b*400+s];
        const float* er = enc + ((size_t)b*400 + s)*512;
        float2 v = *(const float2*)&er[2*t];
        acc0 += a * v.x;
        acc1 += a * v.y;
    }
    atomicAdd(&ctx_ws[b*512 + 2*t],     acc0);
    atomicAdd(&ctx_ws[b*512 + 2*t + 1], acc1);
}

// ---------------- K6: gen_p + out1 = relu(W1 @ [h,ctx] + b1) ----------------
__global__ void k_small2(const float* ctx_ws, const float* status, const float* x_ws,
                         const float* gp_wh, const float* gp_bh,
                         const float* gp_ws_, const float* gp_bs,
                         const float* gp_wx, const float* gp_bx,
                         const float* w1, const float* b1,
                         float* o_ctx, float* o_gp,
                         float* gp_v, u16* out1)
{
    int b = blockIdx.x, t = threadIdx.x;
    __shared__ float feat[768];   // [h_t(256), ctx(512)]
    __shared__ float red[256];
    feat[t] = status[b*512+t];
    for (int i = t; i < 512; i += 256) {
        float c = ctx_ws[b*512+i];
        feat[256+i] = c;
        o_ctx[b*512+i] = c;
    }
    __syncthreads();
    float p = 0.f;
    for (int k = t; k < 512; k += 256) {
        p += gp_wh[k]  * feat[256+k];
        p += gp_ws_[k] * status[b*512+k];
    }
    if (t < 128) p += gp_wx[t] * x_ws[b*128+t];
    red[t] = p; __syncthreads();
    for (int o = 128; o > 0; o >>= 1) { if (t < o) red[t] += red[t+o]; __syncthreads(); }
    if (t == 0) {
        float gp = sigm(red[0] + gp_bh[0] + gp_bs[0] + gp_bx[0]);
        gp_v[b] = gp; o_gp[b] = gp;
    }
    __syncthreads();
    {
        float s = b1[t];
        const float* wr = w1 + t*768;
        for (int k = 0; k < 768; k++) s += wr[k] * feat[k];
        out1[b*256+t] = f2bits(fmaxf(s, 0.f));
    }
}

// ---------------- K7: logits = out1 @ w2^T + b2 (MFMA) -> fp32 into d_out ----------------
__global__ __launch_bounds__(256) void k_logits(const u16* out1, const float* w2,
                                                const float* b2, float* o_fin)
{
    const int N0 = blockIdx.x * 64;
    int t = threadIdx.x, wave = t >> 6, lane = t & 63, quad = lane >> 4, l16 = lane & 15;
    __shared__ __align__(16) u16 As[128*40];
    __shared__ __align__(16) u16 Bs[64*40];
    f32x4 acc[2][4] = {};
    for (int kt = 0; kt < 256; kt += 32) {
        #pragma unroll
        for (int j = 0; j < 2; j++) {           // A: 128 rows x 32 k (bf16), uint4 = 8 u16
            int gi = j*256 + t;
            int row = gi >> 2, c = gi & 3;
            *(uint4*)&As[row*40 + c*8] = *(const uint4*)&out1[row*256 + kt + c*8];
        }
        #pragma unroll
        for (int j = 0; j < 2; j++) {           // B: 64 cols x 32 k (fp32 -> bf16)
            int gi = j*256 + t;
            int col = gi >> 3, c4 = gi & 7;
            int n = N0 + col;
            float4 v = (n < V_) ? *(const float4*)&w2[(size_t)n*256 + kt + c4*4]
                                : make_float4(0.f,0.f,0.f,0.f);
            ushort4 pk = { f2bits(v.x), f2bits(v.y), f2bits(v.z), f2bits(v.w) };
            *(ushort4*)&Bs[col*40 + c4*4] = pk;
        }
        __syncthreads();
        bf16x8 af[2], bfr[4];
        #pragma unroll
        for (int mi = 0; mi < 2; mi++)
            af[mi] = *(const bf16x8*)&As[(wave*32 + mi*16 + l16)*40 + quad*8];
        #pragma unroll
        for (int ni = 0; ni < 4; ni++)
            bfr[ni] = *(const bf16x8*)&Bs[(ni*16 + l16)*40 + quad*8];
        #pragma unroll
        for (int mi = 0; mi < 2; mi++)
            #pragma unroll
            for (int ni = 0; ni < 4; ni++)
                acc[mi][ni] = __builtin_amdgcn_mfma_f32_16x16x32_bf16(af[mi], bfr[ni], acc[mi][ni], 0, 0, 0);
        __syncthreads();
    }
    #pragma unroll
    for (int ni = 0; ni < 4; ni++) {
        int n = N0 + ni*16 + l16;
        if (n < V_) {
            float bias = b2[n];
            #pragma unroll
            for (int mi = 0; mi < 2; mi++) {
                #pragma unroll
                for (int rr = 0; rr < 4; rr++) {
                    int row = wave*32 + mi*16 + quad*4 + rr;
                    o_fin[(size_t)row*VO_ + n] = acc[mi][ni][rr] + bias;
                }
            }
        }
    }
}

// ---------------- K8: per-row PARTIAL online max+sumexp over V, grid (128,8) ----------------
__global__ void k_rowstats(const float* o_fin, float* pm, float* ps)
{
    int b = blockIdx.x, q = blockIdx.y, t = threadIdx.x;
    int i0 = q * 6250, i1 = i0 + 6250;
    float m = -1e30f, s = 0.f;
    const float* lr = o_fin + (size_t)b*VO_;
    for (int i = i0 + t; i < i1; i += 256) {
        float x = lr[i];
        if (x > m) { s = s * __expf(m - x) + 1.f; m = x; }
        else       { s += __expf(x - m); }
    }
    __shared__ float ms[256], ss[256];
    ms[t] = m; ss[t] = s; __syncthreads();
    for (int o = 128; o > 0; o >>= 1) {
        if (t < o) {
            float m2 = fmaxf(ms[t], ms[t+o]);
            ss[t] = ss[t]*__expf(ms[t]-m2) + ss[t+o]*__expf(ms[t+o]-m2);
            ms[t] = m2;
        }
        __syncthreads();
    }
    if (t == 0) { pm[b*8+q] = ms[0]; ps[b*8+q] = ss[0]; }
}

// ---------------- K9a: in-place normalize + OOV tail (combines 8 partials) ----------------
__global__ void k_norm(float* o_fin, const float* pm, const float* ps,
                       const float* gp, const float* oovz)
{
    int b = blockIdx.y;
    int i = blockIdx.x*256 + threadIdx.x;
    if (i >= VO_) return;
    float m = -1e30f;
    #pragma unroll
    for (int q = 0; q < 8; q++) m = fmaxf(m, pm[b*8+q]);
    float s = 0.f;
    #pragma unroll
    for (int q = 0; q < 8; q++) s += ps[b*8+q] * __expf(pm[b*8+q] - m);
    size_t idx = (size_t)b*VO_ + i;
    if (i < V_) {
        float l = o_fin[idx];
        o_fin[idx] = __expf(l - m) * (gp[b] / s);
    } else {
        o_fin[idx] = oovz[b*OOV_ + (i - V_)];
    }
}

// ---------------- K9b: pointer scatter-add (native fp32 atomics) ----------------
__global__ void k_scatter(const int* eoov, const float* a_ws, const float* gp,
                          float* o_fin)
{
    int b = blockIdx.x, t = threadIdx.x;
    float w = 1.f - gp[b];
    for (int s = t; s < 400; s += 256) {
        int idx = eoov[b*400+s];
        float v = a_ws[b*400+s] * w;
        atomicAdd(&o_fin[(size_t)b*VO_ + idx], v);
    }
}

extern "C" void kernel_launch(void* const* d_in, const int* in_sizes, int n_in,
                              void* d_out, int out_size, void* d_ws, size_t ws_size,
                              hipStream_t stream)
{
    const int*   tok  = (const int*)d_in[0];
    const float* h0   = (const float*)d_in[1];
    const float* c0   = (const float*)d_in[2];
    const float* enc  = (const float*)d_in[3];
    const int*   mask = (const int*)d_in[4];
    const float* ctxv = (const float*)d_in[5];
    const float* oovz = (const float*)d_in[6];
    const int*   eoov = (const int*)d_in[7];
    const float* cov  = (const float*)d_in[8];
    const float* emb  = (const float*)d_in[9];
    const float* Wi   = (const float*)d_in[10];
    const float* bi   = (const float*)d_in[11];
    const float* W_ih = (const float*)d_in[12];
    const float* W_hh = (const float*)d_in[13];
    const float* b_ih = (const float*)d_in[14];
    const float* b_hh = (const float*)d_in[15];
    const float* awh  = (const float*)d_in[16];
    const float* aws  = (const float*)d_in[17];
    const float* awc  = (const float*)d_in[18];
    const float* abc  = (const float*)d_in[19];
    const float* av   = (const float*)d_in[20];
    const float* gp_wh= (const float*)d_in[21];
    const float* gp_bh= (const float*)d_in[22];
    const float* gp_ws= (const float*)d_in[23];
    const float* gp_bs= (const float*)d_in[24];
    const float* gp_wx= (const float*)d_in[25];
    const float* gp_bx= (const float*)d_in[26];
    const float* w1   = (const float*)d_in[27];
    const float* b1   = (const float*)d_in[28];
    const float* w2   = (const float*)d_in[29];
    const float* b2   = (const float*)d_in[30];

    // workspace (~1.86 MB)
    char* ws = (char*)d_ws;
    float* ctx_ws = (float*)(ws + 0);          // 65536 f32 (zeroed, atomic)
    float* e_t    = (float*)(ws + 262144);     // 51200 f32 (zeroed, atomic)
    float* status = (float*)(ws + 466944);     // 128*512
    float* x_ws   = (float*)(ws + 729088);     // 128*128
    float* dec_ws = (float*)(ws + 794624);     // 128*512
    float* a_ws   = (float*)(ws + 1056768);    // 128*400
    float* gp_v   = (float*)(ws + 1261568);    // 128
    u16*   out1   = (u16*)  (ws + 1263104);    // 128*256 bf16 -> 1328640
    u16*   wh_bf  = (u16*)  (ws + 1328640);    // 512*512 bf16 -> 1852928
    float* pm     = (float*)(ws + 1852928);    // 128*8 -> 1857024
    float* psum   = (float*)(ws + 1857024);    // 128*8 -> 1861120

    float* out   = (float*)d_out;              // fp32 outputs
    float* o_fin = out;                        // 128*50050
    float* o_ht  = out + 6406400;
    float* o_ct  = out + 6439168;
    float* o_ctx = out + 6471936;
    float* o_at  = out + 6537472;
    float* o_gp  = out + 6588672;
    float* o_cov = out + 6588800;

    k_init<<<dim3(457), 256, 0, stream>>>((float*)ws, 116736);   // ctx_ws + e_t
    k_cvt<<<dim3(256), 256, 0, stream>>>(awh, wh_bf);
    k_small1<<<dim3(128), 256, 0, stream>>>(tok, emb, ctxv, h0, c0, Wi, bi,
                                            W_ih, W_hh, b_ih, b_hh, aws,
                                            o_ht, o_ct, status, x_ws, dec_ws);
    k_attn<<<dim3(800, 2), 256, 0, stream>>>(enc, wh_bf, dec_ws, cov, awc, abc, av, e_t);
    k_softmax_s<<<dim3(128), 256, 0, stream>>>(e_t, mask, cov, a_ws, o_at, o_cov);
    k_ctx<<<dim3(128, 8), 256, 0, stream>>>(a_ws, enc, ctx_ws);
    k_small2<<<dim3(128), 256, 0, stream>>>(ctx_ws, status, x_ws,
                                            gp_wh, gp_bh, gp_ws, gp_bs, gp_wx, gp_bx,
                                            w1, b1, o_ctx, o_gp, gp_v, out1);
    k_logits<<<dim3(782), 256, 0, stream>>>(out1, w2, b2, o_fin);
    k_rowstats<<<dim3(128, 8), 256, 0, stream>>>(o_fin, pm, psum);
    k_norm<<<dim3(196, 128), 256, 0, stream>>>(o_fin, pm, psum, gp_v, oovz);
    k_scatter<<<dim3(128), 256, 0, stream>>>(eoov, a_ws, gp_v, o_fin);
}

// Round 9
// 450.293 us; speedup vs baseline: 1.6483x; 1.2043x over previous
//
#include <hip/hip_runtime.h>
#include <hip/hip_bf16.h>
#include <string.h>

// Sizes
#define V_    50000
#define VO_   50050
#define E_    128
#define H_    256
#define S_    400
#define B_    128
#define OOV_  50

typedef __bf16  bf16x8 __attribute__((ext_vector_type(8)));
typedef float   f32x4  __attribute__((ext_vector_type(4)));
typedef unsigned short u16;
typedef unsigned int   u32;

__device__ __forceinline__ float sigm(float x){ return 1.f/(1.f+__expf(-x)); }
__device__ __forceinline__ float tanh_fast(float x){ float e = __expf(2.f*x); return 1.f - 2.f/(e+1.f); }
__device__ __forceinline__ u16 f2bits(float f){ __hip_bfloat16 h = __float2bfloat16(f); u16 b; memcpy(&b, &h, 2); return b; }

__device__ __forceinline__ float wave_reduce(float s){
    s += __shfl_xor(s, 1);  s += __shfl_xor(s, 2);  s += __shfl_xor(s, 4);
    s += __shfl_xor(s, 8);  s += __shfl_xor(s, 16); s += __shfl_xor(s, 32);
    return s;
}

// async global->LDS DMA, 16 B per lane, LDS dst = wave-uniform base + lane*16
#define ASYNC_COPY16(g, l) \
    __builtin_amdgcn_global_load_lds((const __attribute__((address_space(1))) u32*)(g), \
                                     (__attribute__((address_space(3))) u32*)(l), 16, 0, 0)

// ---------------- K0: zero ctx accumulator + e_t ----------------
__global__ void k_init(float* p, int n){
    int i = blockIdx.x*256 + threadIdx.x;
    if (i < n) p[i] = 0.f;
}

// ---------------- K0b: convert att_wh (512x512 fp32) -> bf16 once ----------------
__global__ void k_cvt(const float* src, u16* dst){
    int i = (blockIdx.x*256 + threadIdx.x) * 4;
    float4 v = *(const float4*)&src[i];
    ushort4 pk = { f2bits(v.x), f2bits(v.y), f2bits(v.z), f2bits(v.w) };
    *(ushort4*)&dst[i] = pk;
}

// ---------------- K1a: x[b][n] = dot(cat(ctxv[b],emb[tok[b]]), Wi[n]) + bi[n] ----------------
// one wave per output; 16384 waves; grid 1024 x 1024thr
__global__ __launch_bounds__(1024) void k_x(const int* tok, const float* emb, const float* ctxv,
                                            const float* Wi, const float* bi, float* x_ws)
{
    int t = threadIdx.x, lane = t & 63;
    int gw = blockIdx.x*16 + (t >> 6);
    int b = gw >> 7, n = gw & 127;
    int tk = tok[b];
    float s = 0.f;
    #pragma unroll
    for (int j = 0; j < 10; j++) {
        int k = lane + j*64;
        float a = (k < 512) ? ctxv[b*512 + k] : emb[tk*128 + (k - 512)];
        s += a * Wi[n*640 + k];
    }
    s = wave_reduce(s);
    if (lane == 0) x_ws[b*128 + n] = s + bi[n];
}

// ---------------- K1b: gates[b][n] = x[b]@W_ih[n] + h0[b]@W_hh[n] + b_ih[n]+b_hh[n] ----------------
// 131072 waves; grid 8192 x 1024thr
__global__ __launch_bounds__(1024) void k_gates(const float* x_ws, const float* h0,
                                                const float* W_ih, const float* W_hh,
                                                const float* b_ih, const float* b_hh,
                                                float* gates_ws)
{
    int t = threadIdx.x, lane = t & 63;
    int gw = blockIdx.x*16 + (t >> 6);
    int b = gw >> 10, n = gw & 1023;
    float s = 0.f;
    #pragma unroll
    for (int j = 0; j < 2; j++) {
        int k = lane + j*64;
        s += x_ws[b*128 + k] * W_ih[n*128 + k];
    }
    #pragma unroll
    for (int j = 0; j < 4; j++) {
        int k = lane + j*64;
        s += h0[b*256 + k] * W_hh[n*256 + k];
    }
    s = wave_reduce(s);
    if (lane == 0) gates_ws[b*1024 + n] = s + b_ih[n] + b_hh[n];
}

// ---------------- K1c: LSTM elementwise ----------------
__global__ void k_lstm(const float* gates_ws, const float* c0,
                       float* o_ht, float* o_ct, float* ws_status)
{
    int b = blockIdx.x, t = threadIdx.x;
    const float* g = gates_ws + b*1024;
    float ig = sigm(g[t]);
    float fg = sigm(g[256+t]);
    float gg = tanhf(g[512+t]);
    float og = sigm(g[768+t]);
    float c  = fg * c0[b*256+t] + ig * gg;
    float h  = og * tanhf(c);
    o_ht[b*256+t] = h; o_ct[b*256+t] = c;
    ws_status[b*512+t] = h; ws_status[b*512+256+t] = c;
}

// ---------------- K1d: dec[b][n] = dot(status[b], aws[n]) ----------------
// 65536 waves; grid 4096 x 1024thr
__global__ __launch_bounds__(1024) void k_dec(const float* status, const float* aws, float* dec_ws)
{
    int t = threadIdx.x, lane = t & 63;
    int gw = blockIdx.x*16 + (t >> 6);
    int b = gw >> 9, n = gw & 511;
    float s = 0.f;
    #pragma unroll
    for (int j = 0; j < 8; j++) {
        int k = lane + j*64;
        s += status[b*512 + k] * aws[n*512 + k];
    }
    s = wave_reduce(s);
    if (lane == 0) dec_ws[b*512 + n] = s;
}

// ---------------- K3: enc_feat GEMM fused tanh+dot(att_v), occupancy-tuned ----------------
// grid (800, 2): block = 64 rows x 256 cols; 4 waves, each 64x64 (acc = 64 AGPR).
__global__ __launch_bounds__(256, 2) void k_attn(
    const float* enc, const u16* whb, const float* dec, const float* cov,
    const float* wc, const float* bc, const float* vv, float* e_t)
{
    const int M0 = blockIdx.x * 64;
    const int N0 = blockIdx.y * 256;
    int t = threadIdx.x;
    int wave = t >> 6, lane = t & 63, quad = lane >> 4, l16 = lane & 15;
    __shared__ __align__(16) u16 As[64*40];     // padded stride 40
    __shared__ __align__(16) u16 Bs[256*32];    // contiguous stride 32 (DMA layout)
    f32x4 acc[4][4] = {};
    const int arow = t >> 2, ac8 = (t & 3) * 8;
    const int brow_l = (lane >> 2);
    const int bkk  = (lane & 3) * 8;
    for (int kt = 0; kt < 512; kt += 32) {
        #pragma unroll
        for (int j = 0; j < 4; j++) {
            int rbase = wave*64 + j*16;
            const u16* src = whb + (size_t)(N0 + rbase + brow_l)*512 + kt + bkk;
            ASYNC_COPY16(src, &Bs[rbase*32]);
        }
        {
            const float* ap = &enc[(size_t)(M0 + arow)*512 + kt + ac8];
            float4 v0 = *(const float4*)ap;
            float4 v1 = *(const float4*)(ap + 4);
            ushort4 p0 = { f2bits(v0.x), f2bits(v0.y), f2bits(v0.z), f2bits(v0.w) };
            ushort4 p1 = { f2bits(v1.x), f2bits(v1.y), f2bits(v1.z), f2bits(v1.w) };
            *(ushort4*)&As[arow*40 + ac8]     = p0;
            *(ushort4*)&As[arow*40 + ac8 + 4] = p1;
        }
        __syncthreads();
        bf16x8 af[4], bfr[4];
        #pragma unroll
        for (int mi = 0; mi < 4; mi++)
            af[mi] = *(const bf16x8*)&As[(mi*16 + l16)*40 + quad*8];
        #pragma unroll
        for (int ni = 0; ni < 4; ni++)
            bfr[ni] = *(const bf16x8*)&Bs[(wave*64 + ni*16 + l16)*32 + quad*8];
        #pragma unroll
        for (int mi = 0; mi < 4; mi++)
            #pragma unroll
            for (int ni = 0; ni < 4; ni++)
                acc[mi][ni] = __builtin_amdgcn_mfma_f32_16x16x32_bf16(af[mi], bfr[ni], acc[mi][ni], 0, 0, 0);
        __syncthreads();
    }
    #pragma unroll
    for (int mi = 0; mi < 4; mi++) {
        #pragma unroll
        for (int rr = 0; rr < 4; rr++) {
            int rl = mi*16 + quad*4 + rr;
            int row = M0 + rl;
            int bb = row / 400;
            float covv = cov[row];
            float psum = 0.f;
            #pragma unroll
            for (int ni = 0; ni < 4; ni++) {
                int d = N0 + wave*64 + ni*16 + l16;
                float arg = acc[mi][ni][rr] + dec[bb*512 + d] + covv * wc[d] + bc[d];
                psum += vv[d] * tanh_fast(arg);
            }
            psum += __shfl_xor(psum, 1);
            psum += __shfl_xor(psum, 2);
            psum += __shfl_xor(psum, 4);
            psum += __shfl_xor(psum, 8);
            if (l16 == 0) atomicAdd(&e_t[row], psum);
        }
    }
}

// ---------------- K4: masked softmax over S + a_t + next_coverage ----------------
__global__ void k_softmax_s(const float* e_t, const int* mask, const float* cov,
                            float* a_ws, float* o_at, float* o_cov)
{
    int b = blockIdx.x, t = threadIdx.x;
    __shared__ float red[256];
    __shared__ float vals[400];
    float m = -1e30f;
    for (int s = t; s < 400; s += 256) {
        float v = (mask[b*400+s] == 0) ? -1e30f : e_t[b*400+s];
        vals[s] = v;
        m = fmaxf(m, v);
    }
    red[t] = m; __syncthreads();
    for (int o = 128; o > 0; o >>= 1) { if (t < o) red[t] = fmaxf(red[t], red[t+o]); __syncthreads(); }
    m = red[0]; __syncthreads();
    float sum = 0.f;
    for (int s = t; s < 400; s += 256) { float e = __expf(vals[s]-m); vals[s] = e; sum += e; }
    red[t] = sum; __syncthreads();
    for (int o = 128; o > 0; o >>= 1) { if (t < o) red[t] += red[t+o]; __syncthreads(); }
    float inv = 1.f / red[0];
    for (int s = t; s < 400; s += 256) {
        float a = vals[s] * inv;
        a_ws[b*400+s] = a;
        o_at[b*400+s] = a;
        o_cov[b*400+s] = cov[b*400+s] + a;
    }
}

// ---------------- K5: ctx = sum_s a[s] * enc[b,s,:] (fp32), grid (128,8) ----------------
__global__ void k_ctx(const float* a_ws, const float* enc, float* ctx_ws)
{
    int b = blockIdx.x, t = threadIdx.x;
    int s0 = blockIdx.y * 50;
    float acc0 = 0.f, acc1 = 0.f;
    for (int s = s0; s < s0+50; s++) {
        float a = a_ws[b*400+s];
        const float* er = enc + ((size_t)b*400 + s)*512;
        float2 v = *(const float2*)&er[2*t];
        acc0 += a * v.x;
        acc1 += a * v.y;
    }
    atomicAdd(&ctx_ws[b*512 + 2*t],     acc0);
    atomicAdd(&ctx_ws[b*512 + 2*t + 1], acc1);
}

// ---------------- K6: gen_p + o_ctx copy (w1 GEMM moved to k_out1) ----------------
__global__ void k_small2(const float* ctx_ws, const float* status, const float* x_ws,
                         const float* gp_wh, const float* gp_bh,
                         const float* gp_ws_, const float* gp_bs,
                         const float* gp_wx, const float* gp_bx,
                         float* o_ctx, float* o_gp, float* gp_v)
{
    int b = blockIdx.x, t = threadIdx.x;
    __shared__ float red[256];
    float p = 0.f;
    for (int k = t; k < 512; k += 256) {
        float c = ctx_ws[b*512+k];
        o_ctx[b*512+k] = c;
        p += gp_wh[k]  * c;
        p += gp_ws_[k] * status[b*512+k];
    }
    if (t < 128) p += gp_wx[t] * x_ws[b*128+t];
    red[t] = p; __syncthreads();
    for (int o = 128; o > 0; o >>= 1) { if (t < o) red[t] += red[t+o]; __syncthreads(); }
    if (t == 0) {
        float gp = sigm(red[0] + gp_bh[0] + gp_bs[0] + gp_bx[0]);
        gp_v[b] = gp; o_gp[b] = gp;
    }
}

// ---------------- K6b: out1[b][n] = relu(dot([h,ctx], w1[n]) + b1[n]) -> bf16 ----------------
// 32768 waves; grid 2048 x 1024thr
__global__ __launch_bounds__(1024) void k_out1(const float* status, const float* ctx_ws,
                                               const float* w1, const float* b1, u16* out1)
{
    int t = threadIdx.x, lane = t & 63;
    int gw = blockIdx.x*16 + (t >> 6);
    int b = gw >> 8, n = gw & 255;
    float s = 0.f;
    #pragma unroll
    for (int j = 0; j < 12; j++) {
        int k = lane + j*64;
        float a = (k < 256) ? status[b*512 + k] : ctx_ws[b*512 + (k - 256)];
        s += a * w1[n*768 + k];
    }
    s = wave_reduce(s);
    if (lane == 0) out1[b*256 + n] = f2bits(fmaxf(s + b1[n], 0.f));
}

// ---------------- K7: logits = out1 @ w2^T + b2 (MFMA) -> fp32 into d_out ----------------
__global__ __launch_bounds__(256) void k_logits(const u16* out1, const float* w2,
                                                const float* b2, float* o_fin)
{
    const int N0 = blockIdx.x * 64;
    int t = threadIdx.x, wave = t >> 6, lane = t & 63, quad = lane >> 4, l16 = lane & 15;
    __shared__ __align__(16) u16 As[128*40];
    __shared__ __align__(16) u16 Bs[64*40];
    f32x4 acc[2][4] = {};
    for (int kt = 0; kt < 256; kt += 32) {
        #pragma unroll
        for (int j = 0; j < 2; j++) {
            int gi = j*256 + t;
            int row = gi >> 2, c = gi & 3;
            *(uint4*)&As[row*40 + c*8] = *(const uint4*)&out1[row*256 + kt + c*8];
        }
        #pragma unroll
        for (int j = 0; j < 2; j++) {
            int gi = j*256 + t;
            int col = gi >> 3, c4 = gi & 7;
            int n = N0 + col;
            float4 v = (n < V_) ? *(const float4*)&w2[(size_t)n*256 + kt + c4*4]
                                : make_float4(0.f,0.f,0.f,0.f);
            ushort4 pk = { f2bits(v.x), f2bits(v.y), f2bits(v.z), f2bits(v.w) };
            *(ushort4*)&Bs[col*40 + c4*4] = pk;
        }
        __syncthreads();
        bf16x8 af[2], bfr[4];
        #pragma unroll
        for (int mi = 0; mi < 2; mi++)
            af[mi] = *(const bf16x8*)&As[(wave*32 + mi*16 + l16)*40 + quad*8];
        #pragma unroll
        for (int ni = 0; ni < 4; ni++)
            bfr[ni] = *(const bf16x8*)&Bs[(ni*16 + l16)*40 + quad*8];
        #pragma unroll
        for (int mi = 0; mi < 2; mi++)
            #pragma unroll
            for (int ni = 0; ni < 4; ni++)
                acc[mi][ni] = __builtin_amdgcn_mfma_f32_16x16x32_bf16(af[mi], bfr[ni], acc[mi][ni], 0, 0, 0);
        __syncthreads();
    }
    #pragma unroll
    for (int ni = 0; ni < 4; ni++) {
        int n = N0 + ni*16 + l16;
        if (n < V_) {
            float bias = b2[n];
            #pragma unroll
            for (int mi = 0; mi < 2; mi++) {
                #pragma unroll
                for (int rr = 0; rr < 4; rr++) {
                    int row = wave*32 + mi*16 + quad*4 + rr;
                    o_fin[(size_t)row*VO_ + n] = acc[mi][ni][rr] + bias;
                }
            }
        }
    }
}

// ---------------- K8: per-row PARTIAL online max+sumexp over V, grid (128,8) ----------------
__global__ void k_rowstats(const float* o_fin, float* pm, float* ps)
{
    int b = blockIdx.x, q = blockIdx.y, t = threadIdx.x;
    int i0 = q * 6250, i1 = i0 + 6250;
    float m = -1e30f, s = 0.f;
    const float* lr = o_fin + (size_t)b*VO_;
    for (int i = i0 + t; i < i1; i += 256) {
        float x = lr[i];
        if (x > m) { s = s * __expf(m - x) + 1.f; m = x; }
        else       { s += __expf(x - m); }
    }
    __shared__ float ms[256], ss[256];
    ms[t] = m; ss[t] = s; __syncthreads();
    for (int o = 128; o > 0; o >>= 1) {
        if (t < o) {
            float m2 = fmaxf(ms[t], ms[t+o]);
            ss[t] = ss[t]*__expf(ms[t]-m2) + ss[t+o]*__expf(ms[t+o]-m2);
            ms[t] = m2;
        }
        __syncthreads();
    }
    if (t == 0) { pm[b*8+q] = ms[0]; ps[b*8+q] = ss[0]; }
}

// ---------------- K9a: in-place normalize + OOV tail (combines 8 partials) ----------------
__global__ void k_norm(float* o_fin, const float* pm, const float* ps,
                       const float* gp, const float* oovz)
{
    int b = blockIdx.y;
    int i = blockIdx.x*256 + threadIdx.x;
    if (i >= VO_) return;
    float m = -1e30f;
    #pragma unroll
    for (int q = 0; q < 8; q++) m = fmaxf(m, pm[b*8+q]);
    float s = 0.f;
    #pragma unroll
    for (int q = 0; q < 8; q++) s += ps[b*8+q] * __expf(pm[b*8+q] - m);
    size_t idx = (size_t)b*VO_ + i;
    if (i < V_) {
        float l = o_fin[idx];
        o_fin[idx] = __expf(l - m) * (gp[b] / s);
    } else {
        o_fin[idx] = oovz[b*OOV_ + (i - V_)];
    }
}

// ---------------- K9b: pointer scatter-add (native fp32 atomics) ----------------
__global__ void k_scatter(const int* eoov, const float* a_ws, const float* gp,
                          float* o_fin)
{
    int b = blockIdx.x, t = threadIdx.x;
    float w = 1.f - gp[b];
    for (int s = t; s < 400; s += 256) {
        int idx = eoov[b*400+s];
        float v = a_ws[b*400+s] * w;
        atomicAdd(&o_fin[(size_t)b*VO_ + idx], v);
    }
}

extern "C" void kernel_launch(void* const* d_in, const int* in_sizes, int n_in,
                              void* d_out, int out_size, void* d_ws, size_t ws_size,
                              hipStream_t stream)
{
    const int*   tok  = (const int*)d_in[0];
    const float* h0   = (const float*)d_in[1];
    const float* c0   = (const float*)d_in[2];
    const float* enc  = (const float*)d_in[3];
    const int*   mask = (const int*)d_in[4];
    const float* ctxv = (const float*)d_in[5];
    const float* oovz = (const float*)d_in[6];
    const int*   eoov = (const int*)d_in[7];
    const float* cov  = (const float*)d_in[8];
    const float* emb  = (const float*)d_in[9];
    const float* Wi   = (const float*)d_in[10];
    const float* bi   = (const float*)d_in[11];
    const float* W_ih = (const float*)d_in[12];
    const float* W_hh = (const float*)d_in[13];
    const float* b_ih = (const float*)d_in[14];
    const float* b_hh = (const float*)d_in[15];
    const float* awh  = (const float*)d_in[16];
    const float* aws  = (const float*)d_in[17];
    const float* awc  = (const float*)d_in[18];
    const float* abc  = (const float*)d_in[19];
    const float* av   = (const float*)d_in[20];
    const float* gp_wh= (const float*)d_in[21];
    const float* gp_bh= (const float*)d_in[22];
    const float* gp_ws= (const float*)d_in[23];
    const float* gp_bs= (const float*)d_in[24];
    const float* gp_wx= (const float*)d_in[25];
    const float* gp_bx= (const float*)d_in[26];
    const float* w1   = (const float*)d_in[27];
    const float* b1   = (const float*)d_in[28];
    const float* w2   = (const float*)d_in[29];
    const float* b2   = (const float*)d_in[30];

    // workspace (~2.4 MB)
    char* ws = (char*)d_ws;
    float* ctx_ws   = (float*)(ws + 0);          // 65536 f32 (zeroed, atomic)
    float* e_t      = (float*)(ws + 262144);     // 51200 f32 (zeroed, atomic)
    float* status   = (float*)(ws + 466944);     // 128*512
    float* x_ws     = (float*)(ws + 729088);     // 128*128
    float* dec_ws   = (float*)(ws + 794624);     // 128*512
    float* a_ws     = (float*)(ws + 1056768);    // 128*400
    float* gp_v     = (float*)(ws + 1261568);    // 128
    u16*   out1     = (u16*)  (ws + 1263104);    // 128*256 bf16
    u16*   wh_bf    = (u16*)  (ws + 1328640);    // 512*512 bf16
    float* pm       = (float*)(ws + 1852928);    // 128*8
    float* psum     = (float*)(ws + 1857024);    // 128*8
    float* gates_ws = (float*)(ws + 1861120);    // 128*1024 -> 2385408

    float* out   = (float*)d_out;
    float* o_fin = out;                        // 128*50050
    float* o_ht  = out + 6406400;
    float* o_ct  = out + 6439168;
    float* o_ctx = out + 6471936;
    float* o_at  = out + 6537472;
    float* o_gp  = out + 6588672;
    float* o_cov = out + 6588800;

    k_init<<<dim3(457), 256, 0, stream>>>((float*)ws, 116736);   // ctx_ws + e_t
    k_cvt<<<dim3(256), 256, 0, stream>>>(awh, wh_bf);
    k_x<<<dim3(1024), 1024, 0, stream>>>(tok, emb, ctxv, Wi, bi, x_ws);
    k_gates<<<dim3(8192), 1024, 0, stream>>>(x_ws, h0, W_ih, W_hh, b_ih, b_hh, gates_ws);
    k_lstm<<<dim3(128), 256, 0, stream>>>(gates_ws, c0, o_ht, o_ct, status);
    k_dec<<<dim3(4096), 1024, 0, stream>>>(status, aws, dec_ws);
    k_attn<<<dim3(800, 2), 256, 0, stream>>>(enc, wh_bf, dec_ws, cov, awc, abc, av, e_t);
    k_softmax_s<<<dim3(128), 256, 0, stream>>>(e_t, mask, cov, a_ws, o_at, o_cov);
    k_ctx<<<dim3(128, 8), 256, 0, stream>>>(a_ws, enc, ctx_ws);
    k_small2<<<dim3(128), 256, 0, stream>>>(ctx_ws, status, x_ws,
                                            gp_wh, gp_bh, gp_ws, gp_bs, gp_wx, gp_bx,
                                            o_ctx, o_gp, gp_v);
    k_out1<<<dim3(2048), 1024, 0, stream>>>(status, ctx_ws, w1, b1, out1);
    k_logits<<<dim3(782), 256, 0, stream>>>(out1, w2, b2, o_fin);
    k_rowstats<<<dim3(128, 8), 256, 0, stream>>>(o_fin, pm, psum);
    k_norm<<<dim3(196, 128), 256, 0, stream>>>(o_fin, pm, psum, gp_v, oovz);
    k_scatter<<<dim3(128), 256, 0, stream>>>(eoov, a_ws, gp_v, o_fin);
}